// Round 6
// baseline (702.207 us; speedup 1.0000x reference)
//
#include <hip/hip_runtime.h>

#define NN 50000
#define NE 800000
#define NBK 1563          // ceil(NN/32) buckets of 32 nodes
#define CAP 704           // bucket capacity (mean 512, +8.5 sigma)

typedef __attribute__((ext_vector_type(8))) short short8;
typedef __attribute__((ext_vector_type(4))) float f32x4;

// ---- bf16 helpers (RTNE) ----
__device__ inline float blo(unsigned u) { return __uint_as_float(u << 16); }
__device__ inline float bhi(unsigned u) { return __uint_as_float(u & 0xffff0000u); }
__device__ inline unsigned short f2b(float f) {
    unsigned u = __float_as_uint(f);
    u += 0x7fff + ((u >> 16) & 1);
    return (unsigned short)(u >> 16);
}
__device__ inline unsigned packrtne(float a, float b) {
    unsigned ua = __float_as_uint(a); ua += 0x7fff + ((ua >> 16) & 1);
    unsigned ub = __float_as_uint(b); ub += 0x7fff + ((ub >> 16) & 1);
    return (ua >> 16) | (ub & 0xffff0000u);
}
__device__ inline uint4 pack8(const float* f) {
    uint4 o;
    o.x = packrtne(f[0], f[1]); o.y = packrtne(f[2], f[3]);
    o.z = packrtne(f[4], f[5]); o.w = packrtne(f[6], f[7]);
    return o;
}

// ---------------- binned fill: degree count + bucket records, both edge sets ----------------
// record: src16 | dloc<<16  (perm baked into set B's src)
__global__ void k_binfill(const int* __restrict__ src, const int* __restrict__ dst,
                          const int* __restrict__ srcb, const int* __restrict__ dstb,
                          const int* __restrict__ perm,
                          int* __restrict__ cntA, int* __restrict__ cntB,
                          int* __restrict__ bcurA, int* __restrict__ bcurB,
                          unsigned* __restrict__ brecA, unsigned* __restrict__ brecB) {
    int i = blockIdx.x * 256 + threadIdx.x;
    if (i < NE) {
        int d = dst[i], s = src[i];
        atomicAdd(&cntA[d], 1);
        int b = d >> 5;
        int p = atomicAdd(&bcurA[b], 1);
        if (p < CAP) brecA[(size_t)b * CAP + p] = (unsigned)s | ((unsigned)(d & 31) << 16);
    } else if (i < 2 * NE) {
        i -= NE;
        int d = dstb[i], s = srcb[i];
        atomicAdd(&cntB[d], 1);
        int b = d >> 5;
        int p = atomicAdd(&bcurB[b], 1);
        if (p < CAP) brecB[(size_t)b * CAP + p] = (unsigned)perm[s] | ((unsigned)(d & 31) << 16);
    }
}

// ---------------- degree finalize + perm-composed branch-b weight table ----------------
__global__ void k_deg_fin(const int* __restrict__ cntA, const int* __restrict__ cntB,
                          const int* __restrict__ perm,
                          float* __restrict__ dinv, float* __restrict__ deginv,
                          float* __restrict__ dinvb, float* __restrict__ dinvbp,
                          float* __restrict__ deginvb, int n) {
    int i = blockIdx.x * 256 + threadIdx.x;
    if (i < n) {
        float d = (float)(cntA[i] + 1);
        dinv[i]  = rsqrtf(d);  deginv[i]  = 1.0f / d;
        float db = (float)(cntB[i] + 1);
        float r = rsqrtf(db);
        dinvb[i] = r; deginvb[i] = 1.0f / db;
        dinvbp[perm[i]] = r;     // weight lookup by perm-baked record src
    }
}

// ---------------- W -> bf16 transposed [col][k] ----------------
__global__ void k_prepw(const float* __restrict__ W0, const float* __restrict__ W1,
                        const float* __restrict__ W2, unsigned short* __restrict__ Wt) {
    int t = blockIdx.x * 256 + threadIdx.x;
    if (t < 3 * 16384) {
        int m = t >> 14, r = t & 16383;
        int k = r >> 7, c = r & 127;
        const float* W = (m == 0) ? W0 : (m == 1) ? W1 : W2;
        Wt[m * 16384 + c * 128 + k] = f2b(W[r]);
    }
}

// ---------------- x -> bf16: xb = x, xmixb = lam*x + (1-lam)*x[perm] ----------------
__global__ void k_xinit(const float4* __restrict__ x4, const int* __restrict__ perm,
                        const float* __restrict__ lamp,
                        uint2* __restrict__ xb, uint2* __restrict__ xmixb) {
    int t = blockIdx.x * 256 + threadIdx.x;
    if (t < NN * 32) {
        int i = t >> 5, c = t & 31;
        float lam = lamp[0], ml = 1.0f - lam;
        float4 a = x4[t];
        float4 b = x4[(size_t)perm[i] * 32 + c];
        uint2 o1; o1.x = packrtne(a.x, a.y); o1.y = packrtne(a.z, a.w);
        xb[t] = o1;
        uint2 o2;
        o2.x = packrtne(fmaf(lam, a.x, ml * b.x), fmaf(lam, a.y, ml * b.y));
        o2.y = packrtne(fmaf(lam, a.z, ml * b.z), fmaf(lam, a.w, ml * b.w));
        xmixb[t] = o2;
    }
}

// ---------------- fused gather + MFMA layer ----------------
// Block = bucket = 32 nodes, 4 waves. In-LDS counting sort of bucket records,
// register-accumulated gather (8 lanes/node), then 3 MFMA passes sharing W.
__global__ __launch_bounds__(256) void k_layer(
    const unsigned short* __restrict__ xf,      // x0 features (gather source + pass3 self)
    unsigned short* __restrict__ xmix,          // in/out
    const float* __restrict__ dinv, const float* __restrict__ deginv,
    const float* __restrict__ dinvb, const float* __restrict__ dinvbp,
    const float* __restrict__ deginvb,
    const unsigned* __restrict__ brecA, const int* __restrict__ bcntA,
    const unsigned* __restrict__ brecB, const int* __restrict__ bcntB,
    const unsigned short* __restrict__ Wt, const float* __restrict__ bias,
    const float* __restrict__ lamp, unsigned short* __restrict__ x0_out, int do_x0) {
    __shared__ unsigned short Wl[16384];        // 32 KiB [col][k] swizzled
    __shared__ unsigned short st[4096];         // 8 KiB staged tile (swizzled)
    __shared__ unsigned short Ag[4096];         // 8 KiB raw A (linear)
    __shared__ unsigned srec[CAP];
    __shared__ int bins[32], boff[33], bcur[32];

    int tid = threadIdx.x;
    uint4* Wl16 = (uint4*)Wl;
    uint4* st16 = (uint4*)st;
    uint4* Ag16 = (uint4*)Ag;
    const uint4* Wg = (const uint4*)Wt;
#pragma unroll
    for (int i = 0; i < 8; ++i) {
        int idx = tid + i * 256;
        Wl16[idx ^ ((idx >> 4) & 7)] = Wg[idx];
    }
    int row0 = blockIdx.x * 32;
    float lam = lamp[0], ml = 1.0f - lam;
    int w = tid >> 6, lane = tid & 63;
    int rt = w & 1, ch = w >> 1;
    int lr = lane & 15, lk = lane >> 4;
    int gnode = w * 8 + (lane >> 3);     // local node 0..31
    int li = lane & 7;                   // chunk lane (owns 16B chunks li, li+8)
    int grow = row0 + gnode;
    float bcol[4];
#pragma unroll
    for (int ct = 0; ct < 4; ++ct) bcol[ct] = bias[(ch * 4 + ct) * 16 + lr];

    auto sortset = [&](const unsigned* br, int cnt) {
        if (tid < 32) bins[tid] = 0;
        __syncthreads();
        for (int t = tid; t < cnt; t += 256) atomicAdd(&bins[(br[t] >> 16) & 31], 1);
        __syncthreads();
        if (w == 0) {
            int v = (lane < 32) ? bins[lane] : 0;
            for (int o = 1; o < 32; o <<= 1) {
                int t2 = __shfl_up(v, o, 64);
                if (lane >= o) v += t2;
            }
            if (lane < 32) {
                int e = v - bins[lane];
                boff[lane] = e; bcur[lane] = e;
                if (lane == 31) boff[32] = v;
            }
        }
        __syncthreads();
        for (int t = tid; t < cnt; t += 256) {
            unsigned r = br[t];
            int p = atomicAdd(&bcur[(r >> 16) & 31], 1);
            srec[p] = r;
        }
        __syncthreads();
    };

#define ACC8(base, v)                                              \
    acc[base+0] = fmaf(wgt, blo(v.x), acc[base+0]);                \
    acc[base+1] = fmaf(wgt, bhi(v.x), acc[base+1]);                \
    acc[base+2] = fmaf(wgt, blo(v.y), acc[base+2]);                \
    acc[base+3] = fmaf(wgt, bhi(v.y), acc[base+3]);                \
    acc[base+4] = fmaf(wgt, blo(v.z), acc[base+4]);                \
    acc[base+5] = fmaf(wgt, bhi(v.z), acc[base+5]);                \
    acc[base+6] = fmaf(wgt, blo(v.w), acc[base+6]);                \
    acc[base+7] = fmaf(wgt, bhi(v.w), acc[base+7]);

    // gather one set into st (and optionally Ag). wtab: per-record weight table.
    auto gatherset = [&](const float* wtab, const float* dntab, const float* dgtab,
                         bool writeAg) {
        float acc[16];
#pragma unroll
        for (int k = 0; k < 16; ++k) acc[k] = 0.f;
        int t0 = boff[gnode], t1 = boff[gnode + 1];
        for (int t = t0; t < t1; ++t) {
            unsigned r = srec[t];
            int s = r & 0xffff;
            float wgt = wtab[s];
            uint4 v0 = *(const uint4*)(xf + (size_t)s * 128 + li * 8);
            uint4 v1 = *(const uint4*)(xf + (size_t)s * 128 + (li + 8) * 8);
            ACC8(0, v0)
            ACC8(8, v1)
        }
        uint4 z = {0u, 0u, 0u, 0u};
        if (grow < NN) {
            float dn = dntab[grow], dg_ = dgtab[grow];
            uint4 m0 = *(const uint4*)(xmix + (size_t)grow * 128 + li * 8);
            uint4 m1 = *(const uint4*)(xmix + (size_t)grow * 128 + (li + 8) * 8);
            float a[16], sv[16];
#pragma unroll
            for (int k = 0; k < 16; ++k) a[k] = acc[k] * dn;
            sv[0] = fmaf(blo(m0.x), dg_, a[0]);  sv[1] = fmaf(bhi(m0.x), dg_, a[1]);
            sv[2] = fmaf(blo(m0.y), dg_, a[2]);  sv[3] = fmaf(bhi(m0.y), dg_, a[3]);
            sv[4] = fmaf(blo(m0.z), dg_, a[4]);  sv[5] = fmaf(bhi(m0.z), dg_, a[5]);
            sv[6] = fmaf(blo(m0.w), dg_, a[6]);  sv[7] = fmaf(bhi(m0.w), dg_, a[7]);
            sv[8] = fmaf(blo(m1.x), dg_, a[8]);  sv[9] = fmaf(bhi(m1.x), dg_, a[9]);
            sv[10] = fmaf(blo(m1.y), dg_, a[10]); sv[11] = fmaf(bhi(m1.y), dg_, a[11]);
            sv[12] = fmaf(blo(m1.z), dg_, a[12]); sv[13] = fmaf(bhi(m1.z), dg_, a[13]);
            sv[14] = fmaf(blo(m1.w), dg_, a[14]); sv[15] = fmaf(bhi(m1.w), dg_, a[15]);
            st16[(gnode * 16 + li) ^ (gnode & 7)]     = pack8(sv);
            st16[(gnode * 16 + li + 8) ^ (gnode & 7)] = pack8(sv + 8);
            if (writeAg) {
                Ag16[gnode * 16 + li]     = pack8(a);
                Ag16[gnode * 16 + li + 8] = pack8(a + 8);
            }
        } else {
            st16[(gnode * 16 + li) ^ (gnode & 7)] = z;
            st16[(gnode * 16 + li + 8) ^ (gnode & 7)] = z;
            if (writeAg) { Ag16[gnode * 16 + li] = z; Ag16[gnode * 16 + li + 8] = z; }
        }
    };

    auto mmpass = [&](f32x4* acc) {
#pragma unroll
        for (int ct = 0; ct < 4; ++ct) {
            float bv = bcol[ct];
            acc[ct] = (f32x4){bv, bv, bv, bv};
        }
#pragma unroll
        for (int kt = 0; kt < 4; ++kt) {
            int k8 = kt * 4 + lk;
            int ar = rt * 16 + lr;
            short8 af = *(const short8*)&st[((ar * 16 + k8) ^ (ar & 7)) * 8];
#pragma unroll
            for (int ct = 0; ct < 4; ++ct) {
                int bc = (ch * 4 + ct) * 16 + lr;
                short8 bf = *(const short8*)&Wl[((bc * 16 + k8) ^ (bc & 7)) * 8];
                acc[ct] = __builtin_amdgcn_mfma_f32_16x16x32_bf16(af, bf, acc[ct], 0, 0, 0);
            }
        }
    };

    int cA = bcntA[blockIdx.x]; if (cA > CAP) cA = CAP;
    int cB = bcntB[blockIdx.x]; if (cB > CAP) cB = CAP;

    f32x4 h[4], g[4];
    // ---- pass 1: h = (A + xmix*dg) W + b ----
    sortset(brecA + (size_t)blockIdx.x * CAP, cA);
    gatherset(dinv, dinv, deginv, true);
    __syncthreads();
    mmpass(h);
    // ---- pass 2: g = (B + xmix*dgb) W + b ; xmix' = lam*relu(h)+(1-lam)*relu(g) ----
    sortset(brecB + (size_t)blockIdx.x * CAP, cB);   // internal barriers cover st reuse
    gatherset(dinvbp, dinvb, deginvb, false);
    __syncthreads();
    mmpass(g);
#pragma unroll
    for (int ct = 0; ct < 4; ++ct) {
        int col = (ch * 4 + ct) * 16 + lr;
#pragma unroll
        for (int j = 0; j < 4; ++j) {
            int gr = row0 + rt * 16 + lk * 4 + j;
            if (gr < NN) {
                float hv = fmaxf(h[ct][j], 0.f), gv = fmaxf(g[ct][j], 0.f);
                xmix[(size_t)gr * 128 + col] = f2b(fmaf(lam, hv, ml * gv));
            }
        }
    }
    // ---- pass 3: x0' = relu((A + x0*dg) W + b) ----
    if (do_x0) {
        __syncthreads();
#pragma unroll
        for (int i2 = 0; i2 < 2; ++i2) {
            int idx = tid + i2 * 256;
            int r = idx >> 4, k8 = idx & 15;
            int gr = row0 + r;
            uint4 o = {0u, 0u, 0u, 0u};
            if (gr < NN) {
                uint4 av = Ag16[idx];
                uint4 xv = *(const uint4*)(xf + (size_t)gr * 128 + k8 * 8);
                float d = deginv[gr];
                o.x = packrtne(fmaf(blo(xv.x), d, blo(av.x)), fmaf(bhi(xv.x), d, bhi(av.x)));
                o.y = packrtne(fmaf(blo(xv.y), d, blo(av.y)), fmaf(bhi(xv.y), d, bhi(av.y)));
                o.z = packrtne(fmaf(blo(xv.z), d, blo(av.z)), fmaf(bhi(xv.z), d, bhi(av.z)));
                o.w = packrtne(fmaf(blo(xv.w), d, blo(av.w)), fmaf(bhi(xv.w), d, bhi(av.w)));
            }
            st16[idx ^ (r & 7)] = o;
        }
        __syncthreads();
        mmpass(g);
#pragma unroll
        for (int ct = 0; ct < 4; ++ct) {
            int col = (ch * 4 + ct) * 16 + lr;
#pragma unroll
            for (int j = 0; j < 4; ++j) {
                int gr = row0 + rt * 16 + lk * 4 + j;
                if (gr < NN)
                    x0_out[(size_t)gr * 128 + col] = f2b(fmaxf(g[ct][j], 0.f));
            }
        }
    }
}

// ---------------- final linear [128->64] + log_softmax (bf16 in, f32 out) ----------------
__global__ __launch_bounds__(256) void k_lin_lsm(
    const unsigned short* __restrict__ X, const float* __restrict__ Wlin,
    const float* __restrict__ blin, float* __restrict__ out) {
    __shared__ __align__(16) float Wl[128 * 64];
    __shared__ float rb[4][128];
    int tid = threadIdx.x;
#pragma unroll
    for (int i = 0; i < 8; ++i)
        ((float4*)Wl)[tid + i * 256] = ((const float4*)Wlin)[tid + i * 256];
    __syncthreads();
    int lane = tid & 63, w = tid >> 6;
    for (int i = blockIdx.x * 4 + w; i < NN; i += gridDim.x * 4) {
        unsigned u = *(const unsigned*)(X + (size_t)i * 128 + lane * 2);
        rb[w][lane * 2]     = blo(u);
        rb[w][lane * 2 + 1] = bhi(u);
        float acc = blin[lane];
#pragma unroll
        for (int k = 0; k < 128; ++k)
            acc = fmaf(rb[w][k], Wl[k * 64 + lane], acc);
        float m = acc;
#pragma unroll
        for (int off = 32; off >= 1; off >>= 1)
            m = fmaxf(m, __shfl_xor(m, off, 64));
        float p = expf(acc - m);
        float s = p;
#pragma unroll
        for (int off = 32; off >= 1; off >>= 1)
            s += __shfl_xor(s, off, 64);
        out[(size_t)i * 64 + lane] = acc - m - logf(s);
    }
}

extern "C" void kernel_launch(void* const* d_in, const int* in_sizes, int n_in,
                              void* d_out, int out_size, void* d_ws, size_t ws_size,
                              hipStream_t stream) {
    const float* x    = (const float*)d_in[0];
    const int*   ei   = (const int*)  d_in[1];
    const int*   eib  = (const int*)  d_in[2];
    const float* lam  = (const float*)d_in[3];
    const int*   perm = (const int*)  d_in[4];
    const float* W0   = (const float*)d_in[5];
    const float* b0   = (const float*)d_in[6];
    const float* W1   = (const float*)d_in[7];
    const float* b1   = (const float*)d_in[8];
    const float* W2   = (const float*)d_in[9];
    const float* b2   = (const float*)d_in[10];
    const float* Wlin = (const float*)d_in[11];
    const float* blin = (const float*)d_in[12];
    float* out = (float*)d_out;

    const int* src  = ei;   const int* dst  = ei + NE;
    const int* srcb = eib;  const int* dstb = eib + NE;

    // ---- workspace layout ----
    char* ws = (char*)d_ws;
    float* dinv    = (float*)ws;                  // N each
    float* deginv  = dinv + NN;
    float* dinvb   = deginv + NN;
    float* dinvbp  = dinvb + NN;
    float* deginvb = dinvbp + NN;
    int* cntA  = (int*)(deginvb + NN);            // contiguous memset block:
    int* cntB  = cntA + NN;                       // cntA,cntB (N), bcurA,bcurB (1600)
    int* bcurA = cntB + NN;
    int* bcurB = bcurA + 1600;
    char* p = (char*)(bcurB + 1600);
    p = (char*)(((size_t)p + 255) & ~(size_t)255);
    unsigned* brecA = (unsigned*)p;               // NBK*CAP each
    unsigned* brecB = brecA + (size_t)NBK * CAP;
    p = (char*)(brecB + (size_t)NBK * CAP);
    p = (char*)(((size_t)p + 255) & ~(size_t)255);
    unsigned short* Wt    = (unsigned short*)p;   // 3 * 16384 bf16
    unsigned short* xb    = Wt + 3 * 16384;       // N*128 bf16 each
    unsigned short* xmixb = xb + (size_t)NN * 128;
    unsigned short* X1    = xmixb + (size_t)NN * 128;
    unsigned short* X2    = X1 + (size_t)NN * 128;

    // ---- build: degrees + buckets (one edge pass), tables, bf16 inputs ----
    hipMemsetAsync(cntA, 0, (2u * NN + 3200u) * sizeof(int), stream);
    k_binfill<<<(2 * NE + 255) / 256, 256, 0, stream>>>(src, dst, srcb, dstb, perm,
                                                        cntA, cntB, bcurA, bcurB,
                                                        brecA, brecB);
    k_deg_fin<<<(NN + 255) / 256, 256, 0, stream>>>(cntA, cntB, perm, dinv, deginv,
                                                    dinvb, dinvbp, deginvb, NN);
    k_prepw<<<192, 256, 0, stream>>>(W0, W1, W2, Wt);
    k_xinit<<<(NN * 32) / 256, 256, 0, stream>>>((const float4*)x, perm, lam,
                                                 (uint2*)xb, (uint2*)xmixb);

    // ---- 3 fused layers ----
    k_layer<<<NBK, 256, 0, stream>>>(xb, xmixb, dinv, deginv, dinvb, dinvbp, deginvb,
                                     brecA, bcurA, brecB, bcurB, Wt, b0, lam, X1, 1);
    k_layer<<<NBK, 256, 0, stream>>>(X1, xmixb, dinv, deginv, dinvb, dinvbp, deginvb,
                                     brecA, bcurA, brecB, bcurB, Wt + 16384, b1, lam, X2, 1);
    k_layer<<<NBK, 256, 0, stream>>>(X2, xmixb, dinv, deginv, dinvb, dinvbp, deginvb,
                                     brecA, bcurA, brecB, bcurB, Wt + 32768, b2, lam,
                                     (unsigned short*)nullptr, 0);

    // ---- logits + log_softmax ----
    k_lin_lsm<<<12500, 256, 0, stream>>>(xmixb, Wlin, blin, out);
}